// Round 1
// baseline (1215.284 us; speedup 1.0000x reference)
//
#include <hip/hip_runtime.h>

// LuGre friction cell, B=4096 sequences x T=2048 serial steps, S=1, H=64.
// Decomposition: 16 lanes per sequence (each lane owns 4 hidden units of the
// 2->64->1 MLP), 65536 threads = 1024 waves = 1 wave per SIMD on MI355X.
// Per step: per-lane 4x(fma,fma,exp,rcp,fma) for w2*tanh contributions,
// 4-stage __shfl_xor reduce over the 16-lane group, then the scalar tail
// (softplus, g via exp(-|v/vs|^alpha), decay exp, clip, F) replicated on the
// 16 lanes. F values are collected one-per-lane and stored coalesced every
// 16 steps.

#define DT 1e-3f

__global__ __launch_bounds__(256) void lugre_kernel(
    const float* __restrict__ x,       // [B, T, 3]
    const float* __restrict__ sigma1,  // [1]
    const float* __restrict__ sigma2,  // [1]
    const float* __restrict__ alpha_p, // [1]
    const float* __restrict__ vs_p,    // [1]
    const float* __restrict__ W1,      // [2, 64] row-major
    const float* __restrict__ b1,      // [64]
    const float* __restrict__ W2,      // [64]
    const float* __restrict__ b2,      // [1]
    float* __restrict__ out,           // [B, T]
    int B, int T)
{
    const int tid  = blockIdx.x * blockDim.x + threadIdx.x;
    const int lane = tid & 15;   // lane within 16-lane group
    const int b    = tid >> 4;   // sequence index
    if (b >= B) return;

    // Per-lane slice of weights: hidden units h = 4*lane + i, i in [0,4)
    float a0[4], a1[4], bb[4], m2w[4];
    float wsum = 0.f;
#pragma unroll
    for (int i = 0; i < 4; ++i) {
        const int h = 4 * lane + i;
        a0[i] = W1[h];        // W1[0][h]
        a1[i] = W1[64 + h];   // W1[1][h]
        bb[i] = b1[h];
        const float w = W2[h];
        wsum += w;            // tanh contribution = w - 2w/(e+1)
        m2w[i] = -2.f * w;
    }

    const float s1v    = fabsf(sigma1[0]);
    const float s2v    = fabsf(sigma2[0]);
    const float alpha  = alpha_p[0];
    const float inv_vs = 1.0f / vs_p[0];
    const float b2v    = b2[0];

    const float* xb   = x + (long)b * T * 3;
    float*       outb = out + (long)b * T;

    float sz = 0.f;
    float Fkeep = 0.f;

    // software-prefetch x one step ahead (hides L1/L2 latency in the chain)
    float vN = xb[0], fcN = xb[1], fsN = xb[2];

    for (int t = 0; t < T; ++t) {
        const float v  = vN;
        const float fc = fcN;
        const float fs = fsN;
        if (t + 1 < T) {  // wave-uniform branch
            const float* xn = xb + 3 * (t + 1);
            vN = xn[0]; fcN = xn[1]; fsN = xn[2];
        }

        // ---- MLP: y = sum_h W2[h]*tanh(v*W1[0,h] + sz*W1[1,h] + b1[h]) + b2
        // tanh(p) = 1 - 2/(exp(2p)+1); fold the "+1" terms into wsum.
        float acc = wsum;
#pragma unroll
        for (int i = 0; i < 4; ++i) {
            const float pre = fmaf(v, a0[i], fmaf(sz, a1[i], bb[i]));
            const float e   = __expf(2.f * pre);          // |pre| <~ 3, no overflow
            const float r   = __builtin_amdgcn_rcpf(e + 1.f);
            acc = fmaf(m2w[i], r, acc);
        }
        // reduce over the 16-lane group (xor butterfly stays inside group)
        acc += __shfl_xor(acc, 1);
        acc += __shfl_xor(acc, 2);
        acc += __shfl_xor(acc, 4);
        acc += __shfl_xor(acc, 8);
        const float y = acc + b2v;

        // sigma_0 = softplus(y), numerically stable
        const float s0 = fmaxf(y, 0.f) + __logf(1.f + __expf(-fabsf(y)));

        // g = F_c + (F_s - F_c) * exp(-|v/v_s|^alpha)
        const float av = fabsf(v);
        const float u  = av * inv_vs;
        const float p  = __expf(alpha * __logf(u)); // u=0 -> log=-inf -> p=0 (matches ref)
        const float w_ = __expf(-p);
        const float g  = fmaf(fs - fc, w_, fc);

        const float k   = copysignf(g, v);          // v==0: decay==1 makes k moot
        const float avg = av * __builtin_amdgcn_rcpf(g);   // |v|/g, g in [~0.5, ~3]
        const float d   = __expf(-DT * s0 * avg);

        const float szn  = fmaf(d, sz - k, k);      // pre-clip sz
        const float zdot = fmaf(-szn, avg, v);      // uses pre-clip sz (as in ref)
        const float szc  = fminf(fmaxf(szn, -fs), fs);
        const float F    = fmaf(s1v, zdot, fmaf(s2v, v, szc));
        sz = szc;

        // collect one F per lane, store coalesced every 16 steps
        if (lane == (t & 15)) Fkeep = F;
        if ((t & 15) == 15) outb[t - 15 + lane] = Fkeep;
    }
}

extern "C" void kernel_launch(void* const* d_in, const int* in_sizes, int n_in,
                              void* d_out, int out_size, void* d_ws, size_t ws_size,
                              hipStream_t stream) {
    const float* x   = (const float*)d_in[0];
    const float* s1  = (const float*)d_in[1];
    const float* s2  = (const float*)d_in[2];
    const float* al  = (const float*)d_in[3];
    const float* vs  = (const float*)d_in[4];
    const float* W1  = (const float*)d_in[5];
    const float* b1  = (const float*)d_in[6];
    const float* W2  = (const float*)d_in[7];
    const float* b2  = (const float*)d_in[8];
    float* out = (float*)d_out;

    const int T = 2048;                 // problem instance: x = [4096, 2048, 3]
    const int B = out_size / T;         // 4096

    const int threads = B * 16;         // 16 lanes per sequence
    const int block   = 256;
    const int grid    = (threads + block - 1) / block;

    lugre_kernel<<<grid, block, 0, stream>>>(x, s1, s2, al, vs, W1, b1, W2, b2,
                                             out, B, T);
}

// Round 2
// 1024.121 us; speedup vs baseline: 1.1867x; 1.1867x over previous
//
#include <hip/hip_runtime.h>

// LuGre friction cell, B=4096 sequences x T=2048 serial steps, S=1, H=64.
// Round 2: 32 lanes per sequence (2 hidden units/lane) -> 2048 waves =
// 2 waves/SIMD (round 1 had 1 wave/SIMD, VALUBusy 35% = latency-bound).
// The 32-lane MLP reduction is 4 DPP adds (quad_perm xor1/xor2, row_ror 4/8,
// all full-rate VALU) + one ds_swizzle for the cross-row-of-16 stage,
// replacing 4 serial ds_swizzles. Weights pre-scaled by 2*log2(e) so the
// tanh exp is a bare v_exp_f32. Decay exp(-DT*s0*|v|/g) (|arg|<0.05) is a
// 3rd-order Horner poly (err ~3e-7/step).

#define DT 1e-3f

template <int CTRL>
__device__ __forceinline__ float dpp_add(float x) {
    int xi = __float_as_int(x);
    int yi = __builtin_amdgcn_update_dpp(xi, xi, CTRL, 0xF, 0xF, true);
    return x + __int_as_float(yi);
}

__global__ __launch_bounds__(256) void lugre_kernel(
    const float* __restrict__ x,       // [B, T, 3]
    const float* __restrict__ sigma1,  // [1]
    const float* __restrict__ sigma2,  // [1]
    const float* __restrict__ alpha_p, // [1]
    const float* __restrict__ vs_p,    // [1]
    const float* __restrict__ W1,      // [2, 64] row-major
    const float* __restrict__ b1,      // [64]
    const float* __restrict__ W2,      // [64]
    const float* __restrict__ b2,      // [1]
    float* __restrict__ out,           // [B, T]
    int B, int T)
{
    const int tid  = blockIdx.x * blockDim.x + threadIdx.x;
    const int lane = tid & 31;   // lane within 32-lane group (= one sequence)
    const int b    = tid >> 5;   // sequence index
    if (b >= B) return;

    const float LOG2E = 1.4426950408889634f;
    const float LN2   = 0.6931471805599453f;
    const float C2    = 2.0f * LOG2E;  // fold exp(2p) -> exp2(C2*p) into weights

    // Per-lane slice: hidden units h = 2*lane + i, i in [0,2)
    float a0[2], a1[2], bb[2], m2w[2];
    float wsum = 0.f;
#pragma unroll
    for (int i = 0; i < 2; ++i) {
        const int h = 2 * lane + i;
        a0[i] = W1[h]      * C2;   // W1[0][h], pre-scaled
        a1[i] = W1[64 + h] * C2;   // W1[1][h], pre-scaled
        bb[i] = b1[h]      * C2;
        const float w = W2[h];
        wsum += w;                 // tanh contribution = w - 2w/(e+1)
        m2w[i] = -2.f * w;
    }

    const float s1v    = fabsf(sigma1[0]);
    const float s2v    = fabsf(sigma2[0]);
    const float alpha  = alpha_p[0];
    const float inv_vs = 1.0f / vs_p[0];
    const float b2v    = b2[0];

    const float* xb   = x + (long)b * T * 3;
    float*       outb = out + (long)b * T;

    float sz = 0.f;
    float Fkeep = 0.f;

    // software-prefetch x one step ahead
    float vN = xb[0], fcN = xb[1], fsN = xb[2];

    for (int t = 0; t < T; ++t) {
        const float v  = vN;
        const float fc = fcN;
        const float fs = fsN;
        if (t + 1 < T) {  // wave-uniform branch
            const float* xn = xb + 3 * (t + 1);
            vN = xn[0]; fcN = xn[1]; fsN = xn[2];
        }

        // ---- v-only path (independent of sz; compiler schedules it early)
        // g = F_c + (F_s - F_c) * exp(-|v/v_s|^alpha)
        const float av = fabsf(v);
        const float u  = av * inv_vs;
        const float lg = __builtin_amdgcn_logf(u);             // log2(u); u=0 -> -inf
        const float p  = __builtin_amdgcn_exp2f(alpha * lg);   // u^alpha;  -> 0
        const float w_ = __builtin_amdgcn_exp2f(-p * LOG2E);   // exp(-p)
        const float g  = fmaf(fs - fc, w_, fc);
        const float k   = copysignf(g, v);
        const float avg = av * __builtin_amdgcn_rcpf(g);       // |v|/g

        // ---- MLP: y = sum_h W2[h]*tanh(v*W1[0,h] + sz*W1[1,h] + b1[h]) + b2
        // tanh(p) = 1 - 2/(exp(2p)+1); "+1" terms folded into wsum.
        float acc = wsum;
#pragma unroll
        for (int i = 0; i < 2; ++i) {
            const float pre = fmaf(v, a0[i], fmaf(sz, a1[i], bb[i])); // already *2log2e
            const float e   = __builtin_amdgcn_exp2f(pre);           // = exp(2*preraw)
            const float r   = __builtin_amdgcn_rcpf(e + 1.f);
            acc = fmaf(m2w[i], r, acc);
        }
        // 32-lane allreduce: 4 DPP adds + 1 swizzle (xor 16)
        acc = dpp_add<0xB1>(acc);   // quad_perm [1,0,3,2]  (xor 1)
        acc = dpp_add<0x4E>(acc);   // quad_perm [2,3,0,1]  (xor 2)
        acc = dpp_add<0x124>(acc);  // row_ror:4
        acc = dpp_add<0x128>(acc);  // row_ror:8
        {
            const int ai = __float_as_int(acc);
            const int bi = __builtin_amdgcn_ds_swizzle(ai, 0x401F); // xor 16
            acc += __int_as_float(bi);
        }
        const float y = acc + b2v;

        // sigma_0 = softplus(y), stable: max(y,0) + ln2*log2(1+exp2(-|y|*log2e))
        const float ay = fabsf(y);
        const float ez = __builtin_amdgcn_exp2f(-ay * LOG2E);
        const float s0 = fmaf(LN2, __builtin_amdgcn_logf(1.f + ez), fmaxf(y, 0.f));

        // d = exp(-DT*s0*avg), |arg| < ~0.05 -> 3rd-order Taylor (err <= x^4/24)
        const float xd = -DT * (s0 * avg);
        const float t1 = fmaf(xd, 0.16666667f, 0.5f);
        const float t2 = fmaf(xd, t1, 1.0f);
        const float d  = fmaf(xd, t2, 1.0f);

        const float szn  = fmaf(d, sz - k, k);        // pre-clip sz
        const float zdot = fmaf(-szn, avg, v);        // uses pre-clip sz (as in ref)
        const float szc  = fminf(fmaxf(szn, -fs), fs);
        const float F    = fmaf(s1v, zdot, fmaf(s2v, v, szc));
        sz = szc;

        // collect one F per lane, store coalesced every 32 steps
        if (lane == (t & 31)) Fkeep = F;
        if ((t & 31) == 31) outb[t - 31 + lane] = Fkeep;
    }
}

extern "C" void kernel_launch(void* const* d_in, const int* in_sizes, int n_in,
                              void* d_out, int out_size, void* d_ws, size_t ws_size,
                              hipStream_t stream) {
    const float* x   = (const float*)d_in[0];
    const float* s1  = (const float*)d_in[1];
    const float* s2  = (const float*)d_in[2];
    const float* al  = (const float*)d_in[3];
    const float* vs  = (const float*)d_in[4];
    const float* W1  = (const float*)d_in[5];
    const float* b1  = (const float*)d_in[6];
    const float* W2  = (const float*)d_in[7];
    const float* b2  = (const float*)d_in[8];
    float* out = (float*)d_out;

    const int T = 2048;                 // problem instance: x = [4096, 2048, 3]
    const int B = out_size / T;         // 4096

    const int threads = B * 32;         // 32 lanes per sequence
    const int block   = 256;
    const int grid    = (threads + block - 1) / block;

    lugre_kernel<<<grid, block, 0, stream>>>(x, s1, s2, al, vs, W1, b1, W2, b2,
                                             out, B, T);
}

// Round 3
// 443.849 us; speedup vs baseline: 2.7381x; 2.3074x over previous
//
#include <hip/hip_runtime.h>

// LuGre friction cell, B=4096 x T=2048 serial steps, S=1, H=64.
// Round 3: the round-2 stall (~530 cyc/step) was exposed HBM latency on the
// x stream (1-step prefetch << 900-cyc miss). Now: batched float4 loads
// (4 steps = 48B per batch, 16B-aligned since 3 float4 per batch), two
// batches in flight -> load-to-use distance ~2500 cyc. L=16 lanes/seq:
// 4 hidden units/lane, reduction = 4 DPP adds within a row of 16 (no LDS).
// 65536 threads = 1024 waves = 1 wave/SIMD.

#define DT 1e-3f

template <int CTRL>
__device__ __forceinline__ float dpp_add(float x) {
    int xi = __float_as_int(x);
    int yi = __builtin_amdgcn_update_dpp(xi, xi, CTRL, 0xF, 0xF, true);
    return x + __int_as_float(yi);
}

__global__ __launch_bounds__(256) void lugre_kernel(
    const float* __restrict__ x,       // [B, T, 3]
    const float* __restrict__ sigma1,  // [1]
    const float* __restrict__ sigma2,  // [1]
    const float* __restrict__ alpha_p, // [1]
    const float* __restrict__ vs_p,    // [1]
    const float* __restrict__ W1,      // [2, 64]
    const float* __restrict__ b1,      // [64]
    const float* __restrict__ W2,      // [64]
    const float* __restrict__ b2,      // [1]
    float* __restrict__ out,           // [B, T]
    int B, int T)
{
    const int tid  = blockIdx.x * blockDim.x + threadIdx.x;
    const int lane = tid & 15;   // lane within 16-lane group (= one DPP row slice)
    const int b    = tid >> 4;   // sequence index
    if (b >= B) return;

    const float LOG2E = 1.4426950408889634f;
    const float C2    = 2.0f * LOG2E;            // exp(2p) = exp2(C2*p)
    const float CD    = -DT * 0.6931471805599453f; // -DT*ln2 (sigma0 kept in log2 domain)

    // Per-lane slice: hidden units h = 4*lane + i.
    // Output weights pre-scaled by LOG2E so the reduced acc is y*log2e.
    float a0[4], a1[4], bb[4], m2w[4];
    float wsum = 0.f;
#pragma unroll
    for (int i = 0; i < 4; ++i) {
        const int h = 4 * lane + i;
        a0[i] = W1[h]      * C2;
        a1[i] = W1[64 + h] * C2;
        bb[i] = b1[h]      * C2;
        const float w = W2[h] * LOG2E;
        wsum += w;                 // tanh = 1 - 2/(e+1); "+1" parts folded here
        m2w[i] = -2.f * w;
    }

    const float s1v    = fabsf(sigma1[0]);
    const float s2v    = fabsf(sigma2[0]);
    const float s12    = s1v + s2v;
    const float alpha  = alpha_p[0];
    const float inv_vs = 1.0f / vs_p[0];
    const float b2l    = b2[0] * LOG2E;   // added AFTER the 16-lane reduce

    // x row for this sequence: 24576 B per row -> float4-aligned.
    const float4* __restrict__ xb4 = (const float4*)(x + (size_t)b * T * 3);
    float* __restrict__ outb = out + (size_t)b * T;

    float sz = 0.f, Fkeep = 0.f;

    // One step of the recurrence
    auto step = [&](float v, float fc, float fs, int tt) {
        // ---- v-only path (off the sz critical chain; scheduler hoists it)
        const float av = fabsf(v);
        const float u  = av * inv_vs;
        const float lg = __builtin_amdgcn_logf(u);            // log2(u)
        const float p  = __builtin_amdgcn_exp2f(alpha * lg);  // u^alpha (u=0 -> 0)
        const float w_ = __builtin_amdgcn_exp2f(-LOG2E * p);  // exp(-p)
        const float g  = fmaf(fs - fc, w_, fc);
        const float k  = copysignf(g, v);
        const float avg = av * __builtin_amdgcn_rcpf(g);      // |v|/g

        // ---- MLP: acc -> y*log2e over the 16-lane group
        float acc = wsum;
#pragma unroll
        for (int i = 0; i < 4; ++i) {
            const float pre = fmaf(v, a0[i], fmaf(sz, a1[i], bb[i]));
            const float e   = __builtin_amdgcn_exp2f(pre);    // exp(2*pre_raw)
            const float r   = __builtin_amdgcn_rcpf(e + 1.f);
            acc = fmaf(m2w[i], r, acc);
        }
        // 16-lane allreduce: pure DPP (quad xor1, xor2, row_ror 4, row_ror 8)
        acc = dpp_add<0xB1>(acc);
        acc = dpp_add<0x4E>(acc);
        acc = dpp_add<0x124>(acc);
        acc = dpp_add<0x128>(acc);
        const float yl = acc + b2l;                           // y * log2e

        // sigma0/ln2 = log2(1 + exp2(yl));  |y| <= ~5 so no overflow
        const float s0p = __builtin_amdgcn_logf(1.f + __builtin_amdgcn_exp2f(yl));

        // d = exp(-DT*sigma0*avg) via 3rd-order Taylor, |arg| < ~0.05
        const float xd = CD * (s0p * avg);
        const float t1 = fmaf(xd, 0.16666667f, 0.5f);
        const float t2 = fmaf(xd, t1, 1.0f);
        const float d  = fmaf(xd, t2, 1.0f);

        const float szn = fmaf(d, sz - k, k);                 // pre-clip sz
        const float szc = fminf(fmaxf(szn, -fs), fs);
        // F = szc + s1*(v - szn*avg) + s2*v = szc + s12*v - (s1*avg)*szn
        const float q = s1v * avg;
        const float F = fmaf(-q, szn, fmaf(s12, v, szc));
        sz = szc;

        if (lane == (tt & 15)) Fkeep = F;
        if ((tt & 15) == 15) outb[tt - 15 + lane] = Fkeep;
    };

    // Process one 4-step batch (3 float4 = steps tb..tb+3)
    auto proc4 = [&](const float4& X0, const float4& X1, const float4& X2, int tb) {
        step(X0.x, X0.y, X0.z, tb);
        step(X0.w, X1.x, X1.y, tb + 1);
        step(X1.z, X1.w, X2.x, tb + 2);
        step(X2.y, X2.z, X2.w, tb + 3);
    };

    const int lastb = T / 4 - 1;   // last batch index

    // Prologue: batches 0 and 1 resident
    float4 A0 = xb4[0], A1 = xb4[1], A2 = xb4[2];
    float4 B0 = xb4[3], B1 = xb4[4], B2 = xb4[5];

    for (int t = 0; t < T; t += 8) {
        const int bk0 = min(t / 4 + 2, lastb);   // prefetch for steps t+8..t+11
        const int bk1 = min(t / 4 + 3, lastb);   // prefetch for steps t+12..t+15
        float4 P0 = xb4[3 * bk0], P1 = xb4[3 * bk0 + 1], P2 = xb4[3 * bk0 + 2];
        float4 Q0 = xb4[3 * bk1], Q1 = xb4[3 * bk1 + 1], Q2 = xb4[3 * bk1 + 2];

        proc4(A0, A1, A2, t);
        proc4(B0, B1, B2, t + 4);

        A0 = P0; A1 = P1; A2 = P2;
        B0 = Q0; B1 = Q1; B2 = Q2;
    }
}

extern "C" void kernel_launch(void* const* d_in, const int* in_sizes, int n_in,
                              void* d_out, int out_size, void* d_ws, size_t ws_size,
                              hipStream_t stream) {
    const float* x   = (const float*)d_in[0];
    const float* s1  = (const float*)d_in[1];
    const float* s2  = (const float*)d_in[2];
    const float* al  = (const float*)d_in[3];
    const float* vs  = (const float*)d_in[4];
    const float* W1  = (const float*)d_in[5];
    const float* b1  = (const float*)d_in[6];
    const float* W2  = (const float*)d_in[7];
    const float* b2  = (const float*)d_in[8];
    float* out = (float*)d_out;

    const int T = 2048;
    const int B = out_size / T;          // 4096

    const int threads = B * 16;          // 16 lanes per sequence
    const int block   = 256;
    const int grid    = (threads + block - 1) / block;

    lugre_kernel<<<grid, block, 0, stream>>>(x, s1, s2, al, vs, W1, b1, W2, b2,
                                             out, B, T);
}

// Round 4
// 416.552 us; speedup vs baseline: 2.9175x; 1.0655x over previous
//
#include <hip/hip_runtime.h>

// LuGre friction cell, B=4096 x T=2048 serial steps, S=1, H=64.
// Round 4: sigma0 = softplus(MLP(v, sz)) is a smooth 2D scalar function with
// a huge error budget (enters F only via exp(-DT*sigma0*|v|/g), DT=1e-3).
// A setup kernel tabulates it on a 128x128 grid (v in [-6.5,6.5], sz in
// [-2.75,2.75]); the main kernel stages the 64 KB table into LDS and does a
// bilinear lookup per step, replacing 4xexp + 4xrcp + DPP-reduce + softplus
// (~114 issue-cyc) with ~45. Bilinear error ~6e-5 in sigma0 -> ~1e-7/step in
// F. Keeps round-3 structure: L=16 lanes/seq (redundant now), 1024 waves =
// 1 wave/SIMD, deep batched float4 prefetch of x.

#define DT 1e-3f

#define NV 128
#define NZ 128
#define VMIN (-6.5f)
#define VMAX (6.5f)
#define ZMIN (-2.75f)
#define ZMAX (2.75f)

__global__ __launch_bounds__(256) void lut_kernel(
    const float* __restrict__ W1,   // [2, 64]
    const float* __restrict__ b1,   // [64]
    const float* __restrict__ W2,   // [64]
    const float* __restrict__ b2,   // [1]
    float* __restrict__ lut)        // [NZ, NV]
{
    const int tid = blockIdx.x * blockDim.x + threadIdx.x;  // 0..NZ*NV-1
    if (tid >= NZ * NV) return;
    const int iz = tid >> 7, iv = tid & (NV - 1);
    const float v  = VMIN + iv * ((VMAX - VMIN) / (NV - 1));
    const float sz = ZMIN + iz * ((ZMAX - ZMIN) / (NZ - 1));

    const float C2 = 2.0f * 1.4426950408889634f;
    float y = b2[0];
#pragma unroll 8
    for (int h = 0; h < 64; ++h) {
        const float pre = fmaf(v, W1[h], fmaf(sz, W1[64 + h], b1[h])) * C2;
        const float e   = __builtin_amdgcn_exp2f(pre);
        const float th  = 1.f - 2.f * __builtin_amdgcn_rcpf(e + 1.f);  // tanh
        y = fmaf(W2[h], th, y);
    }
    // softplus, stable
    const float s0 = fmaxf(y, 0.f) + log1pf(expf(-fabsf(y)));
    lut[tid] = s0;
}

__global__ __launch_bounds__(256) void lugre_kernel(
    const float* __restrict__ x,       // [B, T, 3]
    const float* __restrict__ sigma1,  // [1]
    const float* __restrict__ sigma2,  // [1]
    const float* __restrict__ alpha_p, // [1]
    const float* __restrict__ vs_p,    // [1]
    const float* __restrict__ g_lut,   // [NZ, NV] sigma0 table
    float* __restrict__ out,           // [B, T]
    int B, int T)
{
    __shared__ float lut_s[NZ * NV];   // 64 KB

    // Stage LUT global -> LDS (one-time), float4 coalesced
    {
        const float4* __restrict__ g4 = (const float4*)g_lut;
        float4* __restrict__ l4 = (float4*)lut_s;
        for (int k = threadIdx.x; k < (NZ * NV) / 4; k += 256) l4[k] = g4[k];
    }
    __syncthreads();

    const int tid  = blockIdx.x * blockDim.x + threadIdx.x;
    const int lane = tid & 15;   // lane within 16-lane group
    const int b    = tid >> 4;   // sequence index
    if (b >= B) return;

    const float LOG2E = 1.4426950408889634f;

    const float s1v    = fabsf(sigma1[0]);
    const float s2v    = fabsf(sigma2[0]);
    const float s12    = s1v + s2v;
    const float alpha  = alpha_p[0];
    const float inv_vs = 1.0f / vs_p[0];

    // LUT index transforms: f = (val - MIN) / D, both ranges symmetric -> +63.5
    const float SV = (NV - 1) / (VMAX - VMIN);   // 127/13
    const float SZ = (NZ - 1) / (ZMAX - ZMIN);   // 127/5.5
    const float FMAXV = 126.9999f;

    const float4* __restrict__ xb4 = (const float4*)(x + (size_t)b * T * 3);
    float* __restrict__ outb = out + (size_t)b * T;

    float sz = 0.f, Fkeep = 0.f;

    auto step = [&](float v, float fc, float fs, int tt) {
        // ---- v-only path (independent of sz; schedules early / fills stalls)
        const float av = fabsf(v);
        const float u  = av * inv_vs;
        const float lg = __builtin_amdgcn_logf(u);            // log2(u); u=0 -> -inf
        const float p  = __builtin_amdgcn_exp2f(alpha * lg);  // u^alpha (u=0 -> 0)
        const float w_ = __builtin_amdgcn_exp2f(-LOG2E * p);  // exp(-p)
        const float g  = fmaf(fs - fc, w_, fc);
        const float k  = copysignf(g, v);
        const float avg = av * __builtin_amdgcn_rcpf(g);      // |v|/g
        const float fvr = fminf(fmaxf(fmaf(v, SV, 63.5f), 0.f), FMAXV);
        const float fvf = floorf(fvr);
        const float frv = fvr - fvf;
        const int   ivi = (int)fvf;

        // ---- sigma0 via bilinear LDS LUT on (sz, v)  [sz enters here]
        const float fzr = fminf(fmaxf(fmaf(sz, SZ, 63.5f), 0.f), FMAXV);
        const float fzf = floorf(fzr);
        const float frz = fzr - fzf;
        const int   idx = (int)fzf * NV + ivi;
        const float a0 = lut_s[idx],      a1 = lut_s[idx + 1];
        const float c0 = lut_s[idx + NV], c1 = lut_s[idx + NV + 1];
        const float r0 = fmaf(frv, a1 - a0, a0);
        const float r1 = fmaf(frv, c1 - c0, c0);
        const float s0 = fmaf(frz, r1 - r0, r0);

        // d = exp(-DT*sigma0*avg), |arg| < ~0.05 -> 3rd-order Taylor
        const float xd = -DT * (s0 * avg);
        const float t1 = fmaf(xd, 0.16666667f, 0.5f);
        const float t2 = fmaf(xd, t1, 1.0f);
        const float d  = fmaf(xd, t2, 1.0f);

        const float szn = fmaf(d, sz - k, k);                 // pre-clip sz
        const float szc = fminf(fmaxf(szn, -fs), fs);
        // F = szc + s1*(v - szn*avg) + s2*v
        const float q = s1v * avg;
        const float F = fmaf(-q, szn, fmaf(s12, v, szc));
        sz = szc;

        if (lane == (tt & 15)) Fkeep = F;
        if ((tt & 15) == 15) outb[tt - 15 + lane] = Fkeep;
    };

    auto proc4 = [&](const float4& X0, const float4& X1, const float4& X2, int tb) {
        step(X0.x, X0.y, X0.z, tb);
        step(X0.w, X1.x, X1.y, tb + 1);
        step(X1.z, X1.w, X2.x, tb + 2);
        step(X2.y, X2.z, X2.w, tb + 3);
    };

    const int lastb = T / 4 - 1;

    float4 A0 = xb4[0], A1 = xb4[1], A2 = xb4[2];
    float4 B0 = xb4[3], B1 = xb4[4], B2 = xb4[5];

    for (int t = 0; t < T; t += 8) {
        const int bk0 = min(t / 4 + 2, lastb);
        const int bk1 = min(t / 4 + 3, lastb);
        float4 P0 = xb4[3 * bk0], P1 = xb4[3 * bk0 + 1], P2 = xb4[3 * bk0 + 2];
        float4 Q0 = xb4[3 * bk1], Q1 = xb4[3 * bk1 + 1], Q2 = xb4[3 * bk1 + 2];

        proc4(A0, A1, A2, t);
        proc4(B0, B1, B2, t + 4);

        A0 = P0; A1 = P1; A2 = P2;
        B0 = Q0; B1 = Q1; B2 = Q2;
    }
}

extern "C" void kernel_launch(void* const* d_in, const int* in_sizes, int n_in,
                              void* d_out, int out_size, void* d_ws, size_t ws_size,
                              hipStream_t stream) {
    const float* x   = (const float*)d_in[0];
    const float* s1  = (const float*)d_in[1];
    const float* s2  = (const float*)d_in[2];
    const float* al  = (const float*)d_in[3];
    const float* vs  = (const float*)d_in[4];
    const float* W1  = (const float*)d_in[5];
    const float* b1  = (const float*)d_in[6];
    const float* W2  = (const float*)d_in[7];
    const float* b2  = (const float*)d_in[8];
    float* out = (float*)d_out;
    float* lut = (float*)d_ws;          // NZ*NV floats = 64 KB

    const int T = 2048;
    const int B = out_size / T;         // 4096

    // 1) tabulate sigma0(v, sz) on the 128x128 grid
    lut_kernel<<<(NZ * NV) / 256, 256, 0, stream>>>(W1, b1, W2, b2, lut);

    // 2) recurrence
    const int threads = B * 16;         // 16 lanes per sequence
    const int block   = 256;
    const int grid    = (threads + block - 1) / block;
    lugre_kernel<<<grid, block, 0, stream>>>(x, s1, s2, al, vs, lut, out, B, T);
}

// Round 5
// 399.160 us; speedup vs baseline: 3.0446x; 1.0436x over previous
//
#include <hip/hip_runtime.h>

// LuGre friction cell, B=4096 x T=2048 serial steps, S=1, H=64.
// Round 5: round 4's bilinear sigma0 LUT indexed by (v, sz) put a ~120-cyc
// ds_read on the serial sz-chain (VALUBusy dropped 79->60%). Now sigma0 is
// factored as a quartic in sz with v-dependent coefficients:
//   -DT*sigma0(v,sz) ~= e0(v) + e1(v) sz + ... + e4(v) sz^4
// (Chebyshev 5-node fit in sz over [-2.56,2.56]; sz is clipped to +-F_s<=2.5).
// Coefficients live in a 5 KB LDS table indexed by v only -> fetched and
// lerped ONE BATCH AHEAD (software pipeline), so the recurrence chain is pure
// FMA: Horner(4) -> *avg -> 2-FMA exp Taylor -> szn -> med3 clip (~36 cyc).
// x stream prefetched 3 batches (~900+ cyc) ahead. L=16 lanes/seq (redundant),
// 1024 waves = 1 wave/SIMD.

#define DT 1e-3f
#define NV 256
#define VMINF (-6.6f)
#define VMAXF (6.6f)
#define ZAF   (2.56f)   // Chebyshev half-range in sz

struct Pre { float e0, e1, e2, e3, e4, avg, k, q, sv, fs; };

// ---- setup: per-v-node quartic (in sz) coefficients of -DT*sigma0 ----------
__global__ __launch_bounds__(256) void coef_kernel(
    const float* __restrict__ W1,   // [2,64]
    const float* __restrict__ b1,   // [64]
    const float* __restrict__ W2,   // [64]
    const float* __restrict__ b2,   // [1]
    float4* __restrict__ tabA,      // [NV] (c0,c1,c2,c3) * -DT
    float*  __restrict__ tabB)      // [NV] c4 * -DT
{
    const int iv = threadIdx.x;     // single block of 256
    const float v = VMINF + iv * ((VMAXF - VMINF) / (NV - 1));

    const float pn = 0.95105651629f * ZAF;   // cos(pi/10)*A
    const float qn = 0.58778525229f * ZAF;   // cos(3pi/10)*A
    const float nodes[5] = { pn, -pn, qn, -qn, 0.f };
    float f[5];
#pragma unroll
    for (int j = 0; j < 5; ++j) {
        const float szv = nodes[j];
        float y = b2[0];
        for (int h = 0; h < 64; ++h) {
            const float pre = fmaf(v, W1[h], fmaf(szv, W1[64 + h], b1[h]));
            y = fmaf(W2[h], tanhf(pre), y);
        }
        f[j] = fmaxf(y, 0.f) + log1pf(expf(-fabsf(y)));   // softplus(y)
    }
    // symmetric-node quartic solve
    const float P = pn * pn, Q = qn * qn;
    const float c0 = f[4];
    const float ep = 0.5f * (f[0] + f[1]) - c0;
    const float eq = 0.5f * (f[2] + f[3]) - c0;
    const float op = 0.5f * (f[0] - f[1]);
    const float oq = 0.5f * (f[2] - f[3]);
    const float invPQ = 1.f / (P - Q);
    const float c4 = (ep / P - eq / Q) * invPQ;
    const float c2 = ep / P - c4 * P;
    const float c3 = (op / pn - oq / qn) * invPQ;
    const float c1 = op / pn - c3 * P;
    tabA[iv] = make_float4(-DT * c0, -DT * c1, -DT * c2, -DT * c3);
    tabB[iv] = -DT * c4;
}

// ---- main recurrence -------------------------------------------------------
__global__ __launch_bounds__(256) void lugre_kernel(
    const float* __restrict__ x,       // [B, T, 3]
    const float* __restrict__ sigma1,
    const float* __restrict__ sigma2,
    const float* __restrict__ alpha_p,
    const float* __restrict__ vs_p,
    const float4* __restrict__ tabA,   // [NV]
    const float*  __restrict__ tabB,   // [NV]
    float* __restrict__ out,           // [B, T]
    int B, int T)
{
    __shared__ float4 sA[NV];
    __shared__ float  sB[NV];
    sA[threadIdx.x] = tabA[threadIdx.x];
    sB[threadIdx.x] = tabB[threadIdx.x];
    __syncthreads();

    const int tid  = blockIdx.x * blockDim.x + threadIdx.x;
    const int lane = tid & 15;   // lane within 16-lane group
    const int b    = tid >> 4;   // sequence index
    if (b >= B) return;

    const float LOG2E = 1.4426950408889634f;
    const float s1v    = fabsf(sigma1[0]);
    const float s2v    = fabsf(sigma2[0]);
    const float s12    = s1v + s2v;
    const float alpha  = alpha_p[0];
    const float inv_vs = 1.0f / vs_p[0];
    const float SVC    = (NV - 1) / (VMAXF - VMINF);
    const float VOFF   = -VMINF * SVC;    // 127.5
    const float IMAX   = 254.999f;

    const float4* __restrict__ xb4 = (const float4*)(x + (size_t)b * T * 3);
    float* __restrict__ outb = out + (size_t)b * T;

    float sz = 0.f, Fkeep = 0.f;

    // v-only precompute for one step (off the sz chain; pipelined 1 batch ahead)
    auto mkpre = [&](float v, float fc, float fs) {
        Pre r;
        const float av = fabsf(v);
        const float u  = av * inv_vs;
        const float lg = __builtin_amdgcn_logf(u);            // log2(u); u=0 -> -inf
        const float pw = __builtin_amdgcn_exp2f(alpha * lg);  // u^alpha (u=0 -> 0)
        const float w_ = __builtin_amdgcn_exp2f(-LOG2E * pw); // exp(-u^alpha)
        const float g  = fmaf(fs - fc, w_, fc);
        r.k   = copysignf(g, v);
        r.avg = av * __builtin_amdgcn_rcpf(g);
        r.q   = s1v * r.avg;
        r.sv  = s12 * v;
        r.fs  = fs;
        const float fvr = __builtin_amdgcn_fmed3f(fmaf(v, SVC, VOFF), 0.f, IMAX);
        const float fvf = floorf(fvr);
        const float fr  = fvr - fvf;
        const int   iv  = (int)fvf;
        const float4 A0 = sA[iv], A1 = sA[iv + 1];
        const float  Bc0 = sB[iv], Bc1 = sB[iv + 1];
        r.e0 = fmaf(fr, A1.x - A0.x, A0.x);
        r.e1 = fmaf(fr, A1.y - A0.y, A0.y);
        r.e2 = fmaf(fr, A1.z - A0.z, A0.z);
        r.e3 = fmaf(fr, A1.w - A0.w, A0.w);
        r.e4 = fmaf(fr, Bc1 - Bc0, Bc0);
        return r;
    };

    // serial part of one step: pure FMA chain, no memory
    auto chain = [&](const Pre& P, int tt) {
        const float h  = fmaf(fmaf(fmaf(fmaf(P.e4, sz, P.e3), sz, P.e2), sz, P.e1), sz, P.e0);
        const float xd = h * P.avg;                         // = -DT*sigma0*|v|/g, |xd|<~0.02
        const float d  = fmaf(xd, fmaf(xd, 0.5f, 1.f), 1.f); // exp(xd), err ~ xd^3/6
        const float szn = fmaf(d, sz - P.k, P.k);           // pre-clip sz
        const float szc = __builtin_amdgcn_fmed3f(szn, -P.fs, P.fs);
        const float F   = fmaf(-P.q, szn, P.sv + szc);
        sz = szc;
        if (lane == (tt & 15)) Fkeep = F;
        if ((tt & 15) == 15) outb[tt - 15 + lane] = Fkeep;
    };

    const int lastb = T / 4 - 1;

    // Prologue: x for batches 0..2; pre for batch 0
    float4 A0x = xb4[0], A1x = xb4[1], A2x = xb4[2];
    float4 B0x = xb4[3], B1x = xb4[4], B2x = xb4[5];
    float4 C0x = xb4[6], C1x = xb4[7], C2x = xb4[8];

    Pre pre[4];
    pre[0] = mkpre(A0x.x, A0x.y, A0x.z);
    pre[1] = mkpre(A0x.w, A1x.x, A1x.y);
    pre[2] = mkpre(A1x.z, A1x.w, A2x.x);
    pre[3] = mkpre(A2x.y, A2x.z, A2x.w);

#pragma unroll 4
    for (int n = 0; n < T / 4; ++n) {      // batch n = steps 4n..4n+3
        const int nb = min(n + 3, lastb);  // x prefetch, 3 batches ahead
        const float4 L0 = xb4[3 * nb], L1 = xb4[3 * nb + 1], L2 = xb4[3 * nb + 2];

        // pre for batch n+1 (coef ds_reads land well before next iteration)
        Pre pn0 = mkpre(B0x.x, B0x.y, B0x.z);
        Pre pn1 = mkpre(B0x.w, B1x.x, B1x.y);
        Pre pn2 = mkpre(B1x.z, B1x.w, B2x.x);
        Pre pn3 = mkpre(B2x.y, B2x.z, B2x.w);

        const int t0 = 4 * n;
        chain(pre[0], t0);
        chain(pre[1], t0 + 1);
        chain(pre[2], t0 + 2);
        chain(pre[3], t0 + 3);

        B0x = C0x; B1x = C1x; B2x = C2x;
        C0x = L0;  C1x = L1;  C2x = L2;
        pre[0] = pn0; pre[1] = pn1; pre[2] = pn2; pre[3] = pn3;
    }
}

extern "C" void kernel_launch(void* const* d_in, const int* in_sizes, int n_in,
                              void* d_out, int out_size, void* d_ws, size_t ws_size,
                              hipStream_t stream) {
    const float* x   = (const float*)d_in[0];
    const float* s1  = (const float*)d_in[1];
    const float* s2  = (const float*)d_in[2];
    const float* al  = (const float*)d_in[3];
    const float* vs  = (const float*)d_in[4];
    const float* W1  = (const float*)d_in[5];
    const float* b1  = (const float*)d_in[6];
    const float* W2  = (const float*)d_in[7];
    const float* b2  = (const float*)d_in[8];
    float* out = (float*)d_out;

    float4* tabA = (float4*)d_ws;                       // 4096 B
    float*  tabB = (float*)((char*)d_ws + NV * 16);     // 1024 B

    const int T = 2048;
    const int B = out_size / T;          // 4096

    coef_kernel<<<1, 256, 0, stream>>>(W1, b1, W2, b2, tabA, tabB);

    const int threads = B * 16;          // 16 lanes per sequence
    const int block   = 256;
    const int grid    = (threads + block - 1) / block;
    lugre_kernel<<<grid, block, 0, stream>>>(x, s1, s2, al, vs, tabA, tabB,
                                             out, B, T);
}